// Round 9
// baseline (1297.226 us; speedup 1.0000x reference)
//
#include <hip/hip_runtime.h>
#include <hip/hip_fp16.h>
#include <math.h>

// Problem constants (from reference)
#define B_TRAJ 16384
#define T_STEPS 60
#define D_IN 36
#define L_DIM 10
#define C_NUM 20
#define S_STAT 9
#define OUT_DIM 8
#define TT 2
#define CHT 30                 // steps per xproj chunk (2 chunks)
#define NTILE_C (CHT / TT)     // 15 staging tiles per chunk
#define XTS2 928               // halves per traj chunk buffer (900 used + pad)
                               // stride 1856 B; 1856 mod 128 = 64 -> wave halves 16 banks apart
#define WBF 184                // floats per wave scratch: staging 0..144 (overlays bc YI/R/U/Y),
                               // bcP @ 144..184 (persists across refill)

#define LOG2E 1.4426950408889634f

typedef float f32x2 __attribute__((ext_vector_type(2)));
__device__ __forceinline__ f32x2 pkfma(f32x2 a, f32x2 b, f32x2 c) {
    // llvm.fma.v2f32 -> v_pk_fma_f32 on gfx950 (full-rate packed f32)
    return __builtin_elementwise_fma(a, b, c);
}
__device__ __forceinline__ float rcp_fast(float x) { return __builtin_amdgcn_rcpf(x); }
__device__ __forceinline__ float exp2_fast(float x) { return __builtin_amdgcn_exp2f(x); }
__device__ __forceinline__ float sigm_fast(float x) {
    return rcp_fast(1.0f + exp2_fast(x * -LOG2E));
}
__device__ __forceinline__ float tanh_fast(float x) {
    const float t = fminf(fmaxf(x * (2.0f * LOG2E), -30.0f), 30.0f);
    return fmaf(-2.0f, rcp_fast(exp2_fast(t) + 1.0f), 1.0f);
}
#define WFENCE() __builtin_amdgcn_wave_barrier()

// v14 = v8's proven scan + residency fix.
//  - 128-thread blocks, 4 trajs (2 waves x 2 halves): LDS 9.1 KB -> grid's 16
//    blocks/CU ALL resident (32 waves/CU) if VGPR <= 64; waves_per_eu(6,8)
//    caps VGPR at 85 (v13 lesson: uncapped boundary code hit 132 -> 2 waves/SIMD).
//  - xproj chunked 2x30 steps, refilled WAVE-LOCALLY mid-scan (v8's phase-1
//    staging; weights reloaded per refill behind an opaque barrier).
//  - MLP head accumulated per step: one loop-invariant-address ds_read_b64 of
//    the y-pair (s>>3) + 2-4 L1-hot W_mlp loads + FMA -> y-stash & phase 3 deleted.
// Lane roles (s = lane & 31): s<10 u-col (+ODE col), 10..19 r-col (+emit col),
// 20..29 n-col (+emit col, blend), 30/31 head-only. All scan sync intra-wave.
__global__ __launch_bounds__(128) __attribute__((amdgpu_waves_per_eu(6, 8)))
void dgm2_v14(
    const float* __restrict__ data,        // [B, T, D]
    const float* __restrict__ time_steps,  // [T]
    const float* __restrict__ static_data, // [B, S]
    const float* __restrict__ W_update,    // [46, 10]
    const float* __restrict__ b_update,
    const float* __restrict__ W_reset,     // [46, 10]
    const float* __restrict__ b_reset,
    const float* __restrict__ W_new,       // [46, 10]
    const float* __restrict__ b_new,
    const float* __restrict__ W_emit,      // [30, 20]
    const float* __restrict__ b_emit,
    const float* __restrict__ W_ode,       // [10, 10]
    const float* __restrict__ b_ode,
    const float* __restrict__ W_mlp,       // [609, 8]
    const float* __restrict__ b_mlp,
    float* __restrict__ out)               // [B, 8]
{
    __shared__ __align__(16) __half xprojH[4 * XTS2];  // 7424 B
    __shared__ __align__(16) float wbuf[2][WBF];       // 1472 B
    __shared__ float dts[T_STEPS];                     //  240 B => 9136 B total

    const int tid  = threadIdx.x;
    const int w    = tid >> 6;
    const int lane = tid & 63;
    const int half = lane >> 5;
    const int s    = lane & 31;
    const int ltraj = w * 2 + half;
    const int traj  = blockIdx.x * 4 + ltraj;
    __half* xpj = xprojH + ltraj * XTS2;

    if (tid < T_STEPS) dts[tid] = (tid == 0) ? 0.01f : time_steps[tid] - time_steps[tid - 1];
    __syncthreads();

    // lane roles (v8)
    const bool uo = (s < 10);
    const bool ro = (s >= 10 && s < 20);
    const bool no = (s >= 20 && s < 30);
    const bool eo = (s >= 10 && s < 30);
    const int  gcol = uo ? s : (ro ? (s - 10) : (no ? (s - 20) : 0));
    const float* Wg = uo ? W_update : (ro ? W_reset : W_new);   // s>=30 -> W_new col 0 (harmless)

    // ---- scan weights (v8) ----
    f32x2 wgy2[5];
#pragma unroll
    for (int j = 0; j < 5; ++j)
        wgy2[j] = (f32x2){Wg[(2 * j) * L_DIM + gcol], Wg[(2 * j + 1) * L_DIM + gcol]};

    f32x2 waux2[15];    // eo: emit col (0..9 z-part, 10..14 y-part); uo: 0..4 ODE col
#pragma unroll
    for (int j = 0; j < 15; ++j) {
        float v0 = 0.0f, v1 = 0.0f;
        if (eo)               { v0 = W_emit[(2 * j) * C_NUM + (s - 10)];
                                v1 = W_emit[(2 * j + 1) * C_NUM + (s - 10)]; }
        else if (uo && j < 5) { v0 = W_ode[(2 * j) * L_DIM + s];
                                v1 = W_ode[(2 * j + 1) * L_DIM + s]; }
        waux2[j] = (f32x2){v0, v1};
    }
    const float bode  = uo ? b_ode[s] : 0.0f;
    const float bemit = eo ? b_emit[s - 10] : 0.0f;

    // ---- head setup: lane s -> col = s&7, y-pair = s>>3 (pair 4 on kq==0 lanes) ----
    const int hcol = s & 7;
    const int kq   = s >> 3;
    const int boff = 2 * kq * OUT_DIM + hcol;   // loop-invariant W_mlp row offset
    const int hoff = 2 * kq;                    // loop-invariant bcY offset
    float phead = 0.0f;

    // per-wave bc views (bcP OUT of the 0..144 staging overlay)
    float* wb   = &wbuf[w][0];
    float* bcYI = wb + 0   + half * 12;
    float* bcR  = wb + 24  + half * 12;
    float* bcU  = wb + 48  + half * 12;
    float* bcY  = wb + 72  + half * 12;
    float* bcP  = wb + 144 + half * 20;

    auto ldvec = [&](const float* p, f32x2* d) {
        const float4 a = *reinterpret_cast<const float4*>(p);
        const float4 b = *reinterpret_cast<const float4*>(p + 4);
        const float2 c = *reinterpret_cast<const float2*>(p + 8);
        d[0] = (f32x2){a.x, a.y}; d[1] = (f32x2){a.z, a.w};
        d[2] = (f32x2){b.x, b.y}; d[3] = (f32x2){b.z, b.w};
        d[4] = (f32x2){c.x, c.y};
    };

    // ---- wave-local xproj refill for chunk c (v8 phase-1 machinery) ----
    auto refill = [&](int c) {
        asm volatile("" ::: "memory");        // hoist barrier: keep loads inside
        int off = 0;
        asm volatile("" : "+v"(off));         // opaque 0: no CSE across chunks
        f32x2 wxp2[18];                       // x-part rows 10..45 (transient)
#pragma unroll
        for (int j = 0; j < 18; ++j)
            wxp2[j] = (f32x2){Wg[(L_DIM + 2 * j) * L_DIM + gcol + off],
                              Wg[(L_DIM + 2 * j + 1) * L_DIM + gcol + off]};
        float bcol = 0.0f;                    // gate bias folded into xproj
        if (uo)      bcol = b_update[s];
        else if (ro) bcol = b_reset[s - 10];
        else if (no) bcol = b_new[s - 20];

        float* xst = wb;                      // staging [half][tt][36] @ 0..144
        const float* tbase = data + (size_t)(blockIdx.x * 4 + w * 2) * (T_STEPS * D_IN);
        const int sh  = lane / 18;
        const int sr  = lane % 18;
        const int stt = sr / 9;
        const int scq = sr % 9;
        const bool stg = (lane < 36);
        const int cbase = c * CHT;

        if (stg) {
            const float4 v = *reinterpret_cast<const float4*>(
                tbase + (size_t)sh * (T_STEPS * D_IN) + (cbase + stt) * D_IN + scq * 4);
            *reinterpret_cast<float4*>(xst + (sh * TT + stt) * 36 + scq * 4) = v;
        }
        WFENCE();

#pragma unroll 1
        for (int tile = 0; tile < NTILE_C; ++tile) {
            float4 pf = make_float4(0.f, 0.f, 0.f, 0.f);
            const bool more = stg && (tile + 1 < NTILE_C);
            if (more) {
                pf = *reinterpret_cast<const float4*>(
                    tbase + (size_t)sh * (T_STEPS * D_IN)
                          + (cbase + (tile + 1) * TT + stt) * D_IN + scq * 4);
            }
#pragma unroll
            for (int tt = 0; tt < TT; ++tt) {
                const float* xrow = xst + (half * TT + tt) * 36;
                f32x2 acc2 = (f32x2){bcol, 0.0f};
#pragma unroll
                for (int cq = 0; cq < 9; ++cq) {
                    const float4 x4 = *reinterpret_cast<const float4*>(xrow + cq * 4);
                    acc2 = pkfma((f32x2){x4.x, x4.y}, wxp2[2 * cq],     acc2);
                    acc2 = pkfma((f32x2){x4.z, x4.w}, wxp2[2 * cq + 1], acc2);
                }
                if (s < 30) xpj[(tile * TT + tt) * 30 + s] = __float2half(acc2.x + acc2.y);
            }
            WFENCE();   // all lanes done reading this tile before overwrite
            if (more) {
                *reinterpret_cast<float4*>(xst + (sh * TT + stt) * 36 + scq * 4) = pf;
            }
            WFENCE();   // staged writes visible before next tile's reads
        }
    };

    // ---- init scan state ----
    f32x2 y2[5];
#pragma unroll
    for (int k = 0; k < 5; ++k) y2[k] = (f32x2){0.0f, 0.0f};
    float yown = 0.0f;
    if (eo) bcP[s - 10] = 0.0f;     // carried unnormalized z; 0 => p=0 at t=0
    WFENCE();

    refill(0);
    WFENCE();

    // ================= Scan: 2 chunks x 30 steps =================
#pragma unroll 1
    for (int c = 0; c < 2; ++c) {
#pragma unroll 1
        for (int tt = 0; tt < CHT; ++tt) {
            const int t = c * CHT + tt;
            const float dt = dts[t];

            // ---- ODE: yi_q = y_q + tanh(b + y.Wode[:,q])*dt (meaningful on uo) ----
            f32x2 g2 = (f32x2){bode, 0.0f};
#pragma unroll
            for (int k = 0; k < 5; ++k) g2 = pkfma(y2[k], waux2[k], g2);
            const float yis = fmaf(tanh_fast(g2.x + g2.y), dt, yown);
            if (uo) bcYI[s] = yis;
            WFENCE();
            f32x2 yi2[5];
            ldvec(bcYI, yi2);
            const float yi_g = bcYI[gcol];   // own-column yi (scalar, parallel read)

            // ---- gates: pre-activation = xproj(f16, bias folded) + yi-part ----
            const float xa = __half2float(xpj[tt * 30 + s]);  // s>=30 reads pad, unused
            f32x2 ay2 = (f32x2){xa, 0.0f};
#pragma unroll
            for (int k = 0; k < 5; ++k) ay2 = pkfma(yi2[k], wgy2[k], ay2);
            const float uval = sigm_fast(ay2.x + ay2.y);   // u on uo, r on ro
            if (ro) bcR[s - 10] = uval * yi_g;             // publish yr_k = r_k * yi_k
            if (uo) bcU[s] = uval;                         // publish u_k (same fence)
            WFENCE();
            f32x2 yr2[5];
            ldvec(bcR, yr2);

            // ---- candidate + blend on n-lanes: yn = n + u*(yi - n) ----
            f32x2 n2 = (f32x2){xa, 0.0f};
#pragma unroll
            for (int k = 0; k < 5; ++k) n2 = pkfma(yr2[k], wgy2[k], n2);
            const float accN = n2.x + n2.y;
            const float u_n  = bcU[gcol];
            const float yn   = fmaf(u_n, yi_g - accN, accN);
            if (no) bcY[s - 20] = yn;
            WFENCE();
            ldvec(bcY, y2);
            yown = bcY[gcol];                              // carry for next ODE (uo)

            // ---- head: phead += y_pair(kq) . W_mlp rows (loop-invariant addrs) ----
            {
                const float* wr = W_mlp + (size_t)t * (L_DIM * OUT_DIM);
                const f32x2 yh = *reinterpret_cast<const f32x2*>(bcY + hoff);
                phead = fmaf(yh.x, wr[boff], phead);
                phead = fmaf(yh.y, wr[boff + OUT_DIM], phead);
                if (kq == 0) {   // pair 4 (y8,y9) on the col's first lane
                    phead = fmaf(y2[4].x, wr[8 * OUT_DIM + hcol], phead);
                    phead = fmaf(y2[4].y, wr[9 * OUT_DIM + hcol], phead);
                }
            }

            // ---- emitter: logit = b + (z_prev . We_p)/sum(z) + y . We_y ----
            f32x2 zz[10];
#pragma unroll
            for (int j = 0; j < 5; ++j) {
                const float4 z = *reinterpret_cast<const float4*>(bcP + j * 4);
                zz[2 * j] = (f32x2){z.x, z.y}; zz[2 * j + 1] = (f32x2){z.z, z.w};
            }
            f32x2 zd2 = (f32x2){0.0f, 0.0f};
            f32x2 zs2 = (f32x2){0.0f, 0.0f};
#pragma unroll
            for (int j = 0; j < 10; ++j) {
                zd2 = pkfma(zz[j], waux2[j], zd2);
                zs2 = zs2 + zz[j];
            }
            const float pinv = (t == 0) ? 0.0f : rcp_fast(zs2.x + zs2.y);
            f32x2 ev2 = (f32x2){fmaf(zd2.x + zd2.y, pinv, bemit), 0.0f};
#pragma unroll
            for (int k = 0; k < 5; ++k) ev2 = pkfma(y2[k], waux2[10 + k], ev2);
            const float zv = exp2_fast(fminf((ev2.x + ev2.y) * LOG2E, 86.0f));
            if (eo) bcP[s - 10] = zv;
            // no trailing fence: next step's fences precede the z read; bcP is
            // outside the refill staging region, so it survives the chunk boundary.
        }
        if (c == 0) {
            refill(1);      // wave-local; scan state lives in regs + bcP only
            WFENCE();
        }
    }

    // ================= Epilogue: reduce head partials, add static =================
    phead += __shfl_xor(phead, 8, 32);
    phead += __shfl_xor(phead, 16, 32);
    if (s < OUT_DIM) {
        const float* stp = static_data + (size_t)traj * S_STAT;
        const float* wms = W_mlp + (size_t)(T_STEPS * L_DIM) * OUT_DIM;
        float o = phead;
#pragma unroll
        for (int i = 0; i < S_STAT; ++i) o += stp[i] * wms[i * OUT_DIM + s];
        out[(size_t)traj * OUT_DIM + s] = o + b_mlp[s];
    }
}

extern "C" void kernel_launch(void* const* d_in, const int* in_sizes, int n_in,
                              void* d_out, int out_size, void* d_ws, size_t ws_size,
                              hipStream_t stream) {
    const float* data        = (const float*)d_in[0];
    const float* time_steps  = (const float*)d_in[1];
    const float* static_data = (const float*)d_in[2];
    const float* W_update    = (const float*)d_in[3];
    const float* b_update    = (const float*)d_in[4];
    const float* W_reset     = (const float*)d_in[5];
    const float* b_reset     = (const float*)d_in[6];
    const float* W_new       = (const float*)d_in[7];
    const float* b_new       = (const float*)d_in[8];
    const float* W_emit      = (const float*)d_in[9];
    const float* b_emit      = (const float*)d_in[10];
    const float* W_ode       = (const float*)d_in[11];
    const float* b_ode       = (const float*)d_in[12];
    const float* W_mlp       = (const float*)d_in[13];
    const float* b_mlp       = (const float*)d_in[14];
    float* out = (float*)d_out;

    // 4 trajectories per 128-thread block (2 waves) -> 4096 blocks
    dim3 grid(B_TRAJ / 4), block(128);
    hipLaunchKernelGGL(dgm2_v14, grid, block, 0, stream,
                       data, time_steps, static_data,
                       W_update, b_update, W_reset, b_reset, W_new, b_new,
                       W_emit, b_emit, W_ode, b_ode, W_mlp, b_mlp, out);
}

// Round 10
// 606.194 us; speedup vs baseline: 2.1400x; 2.1400x over previous
//
#include <hip/hip_runtime.h>
#include <hip/hip_fp16.h>
#include <math.h>

// Problem constants (from reference)
#define B_TRAJ 16384
#define T_STEPS 60
#define D_IN 36
#define L_DIM 10
#define C_NUM 20
#define S_STAT 9
#define OUT_DIM 8
#define TT 2
#define CHT 30                 // steps per xproj chunk (2 chunks)
#define NTILE_C (CHT / TT)     // 15 staging tiles per chunk
#define XTS2 928               // halves per traj chunk buffer (900 used + pad)
                               // stride 1856 B; 1856 mod 128 = 64 -> wave halves 16 banks apart
#define WBF 184                // floats per wave scratch: staging 0..144 (overlays bc YI/R/U/Y),
                               // bcP @ 144..184 (persists across refill)

#define LOG2E 1.4426950408889634f

typedef float f32x2 __attribute__((ext_vector_type(2)));
__device__ __forceinline__ f32x2 pkfma(f32x2 a, f32x2 b, f32x2 c) {
    // llvm.fma.v2f32 -> v_pk_fma_f32 on gfx950 (full-rate packed f32)
    return __builtin_elementwise_fma(a, b, c);
}
__device__ __forceinline__ float rcp_fast(float x) { return __builtin_amdgcn_rcpf(x); }
__device__ __forceinline__ float exp2_fast(float x) { return __builtin_amdgcn_exp2f(x); }
__device__ __forceinline__ float sigm_fast(float x) {
    return rcp_fast(1.0f + exp2_fast(x * -LOG2E));
}
__device__ __forceinline__ float tanh_fast(float x) {
    const float t = fminf(fmaxf(x * (2.0f * LOG2E), -30.0f), 30.0f);
    return fmaf(-2.0f, rcp_fast(exp2_fast(t) + 1.0f), 1.0f);
}
#define WFENCE() __builtin_amdgcn_wave_barrier()

// v15 = v14 with the register-allocation bug fixed.
// v14's amdgpu_waves_per_eu(6,8) made the compiler target 8 waves/EU -> 40 VGPR
// -> 3.3 GB of scratch spill traffic (FETCH 2.46 GB, WRITE 734 MB). v15 uses
// __launch_bounds__(128, 4): VGPR ceiling 128 > ~105 peak demand -> no spills,
// 4 waves/EU = 16 waves/CU (vs v8's 13). Everything else identical to v14:
//  - 128-thread blocks, 4 trajs; LDS 9.1 KB (never the occupancy binder).
//  - xproj chunked 2x30 steps, refilled WAVE-LOCALLY mid-scan.
//  - MLP head accumulated per step (y-stash & phase 3 deleted).
// Lane roles (s = lane & 31): s<10 u-col (+ODE col), 10..19 r-col (+emit col),
// 20..29 n-col (+emit col, blend), 30/31 head-only. All scan sync intra-wave.
__global__ __launch_bounds__(128, 4)
void dgm2_v15(
    const float* __restrict__ data,        // [B, T, D]
    const float* __restrict__ time_steps,  // [T]
    const float* __restrict__ static_data, // [B, S]
    const float* __restrict__ W_update,    // [46, 10]
    const float* __restrict__ b_update,
    const float* __restrict__ W_reset,     // [46, 10]
    const float* __restrict__ b_reset,
    const float* __restrict__ W_new,       // [46, 10]
    const float* __restrict__ b_new,
    const float* __restrict__ W_emit,      // [30, 20]
    const float* __restrict__ b_emit,
    const float* __restrict__ W_ode,       // [10, 10]
    const float* __restrict__ b_ode,
    const float* __restrict__ W_mlp,       // [609, 8]
    const float* __restrict__ b_mlp,
    float* __restrict__ out)               // [B, 8]
{
    __shared__ __align__(16) __half xprojH[4 * XTS2];  // 7424 B
    __shared__ __align__(16) float wbuf[2][WBF];       // 1472 B
    __shared__ float dts[T_STEPS];                     //  240 B => 9136 B total

    const int tid  = threadIdx.x;
    const int w    = tid >> 6;
    const int lane = tid & 63;
    const int half = lane >> 5;
    const int s    = lane & 31;
    const int ltraj = w * 2 + half;
    const int traj  = blockIdx.x * 4 + ltraj;
    __half* xpj = xprojH + ltraj * XTS2;

    if (tid < T_STEPS) dts[tid] = (tid == 0) ? 0.01f : time_steps[tid] - time_steps[tid - 1];
    __syncthreads();

    // lane roles (v8)
    const bool uo = (s < 10);
    const bool ro = (s >= 10 && s < 20);
    const bool no = (s >= 20 && s < 30);
    const bool eo = (s >= 10 && s < 30);
    const int  gcol = uo ? s : (ro ? (s - 10) : (no ? (s - 20) : 0));
    const float* Wg = uo ? W_update : (ro ? W_reset : W_new);   // s>=30 -> W_new col 0 (harmless)

    // ---- scan weights (v8) ----
    f32x2 wgy2[5];
#pragma unroll
    for (int j = 0; j < 5; ++j)
        wgy2[j] = (f32x2){Wg[(2 * j) * L_DIM + gcol], Wg[(2 * j + 1) * L_DIM + gcol]};

    f32x2 waux2[15];    // eo: emit col (0..9 z-part, 10..14 y-part); uo: 0..4 ODE col
#pragma unroll
    for (int j = 0; j < 15; ++j) {
        float v0 = 0.0f, v1 = 0.0f;
        if (eo)               { v0 = W_emit[(2 * j) * C_NUM + (s - 10)];
                                v1 = W_emit[(2 * j + 1) * C_NUM + (s - 10)]; }
        else if (uo && j < 5) { v0 = W_ode[(2 * j) * L_DIM + s];
                                v1 = W_ode[(2 * j + 1) * L_DIM + s]; }
        waux2[j] = (f32x2){v0, v1};
    }
    const float bode  = uo ? b_ode[s] : 0.0f;
    const float bemit = eo ? b_emit[s - 10] : 0.0f;

    // ---- head setup: lane s -> col = s&7, y-pair = s>>3 (pair 4 on kq==0 lanes) ----
    const int hcol = s & 7;
    const int kq   = s >> 3;
    const int boff = 2 * kq * OUT_DIM + hcol;   // loop-invariant W_mlp row offset
    const int hoff = 2 * kq;                    // loop-invariant bcY offset
    float phead = 0.0f;

    // per-wave bc views (bcP OUT of the 0..144 staging overlay)
    float* wb   = &wbuf[w][0];
    float* bcYI = wb + 0   + half * 12;
    float* bcR  = wb + 24  + half * 12;
    float* bcU  = wb + 48  + half * 12;
    float* bcY  = wb + 72  + half * 12;
    float* bcP  = wb + 144 + half * 20;

    auto ldvec = [&](const float* p, f32x2* d) {
        const float4 a = *reinterpret_cast<const float4*>(p);
        const float4 b = *reinterpret_cast<const float4*>(p + 4);
        const float2 c = *reinterpret_cast<const float2*>(p + 8);
        d[0] = (f32x2){a.x, a.y}; d[1] = (f32x2){a.z, a.w};
        d[2] = (f32x2){b.x, b.y}; d[3] = (f32x2){b.z, b.w};
        d[4] = (f32x2){c.x, c.y};
    };

    // ---- wave-local xproj refill for chunk c (v8 phase-1 machinery) ----
    auto refill = [&](int c) {
        asm volatile("" ::: "memory");        // hoist barrier: keep loads inside
        int off = 0;
        asm volatile("" : "+v"(off));         // opaque 0: no CSE across chunks
        f32x2 wxp2[18];                       // x-part rows 10..45 (transient)
#pragma unroll
        for (int j = 0; j < 18; ++j)
            wxp2[j] = (f32x2){Wg[(L_DIM + 2 * j) * L_DIM + gcol + off],
                              Wg[(L_DIM + 2 * j + 1) * L_DIM + gcol + off]};
        float bcol = 0.0f;                    // gate bias folded into xproj
        if (uo)      bcol = b_update[s];
        else if (ro) bcol = b_reset[s - 10];
        else if (no) bcol = b_new[s - 20];

        float* xst = wb;                      // staging [half][tt][36] @ 0..144
        const float* tbase = data + (size_t)(blockIdx.x * 4 + w * 2) * (T_STEPS * D_IN);
        const int sh  = lane / 18;
        const int sr  = lane % 18;
        const int stt = sr / 9;
        const int scq = sr % 9;
        const bool stg = (lane < 36);
        const int cbase = c * CHT;

        if (stg) {
            const float4 v = *reinterpret_cast<const float4*>(
                tbase + (size_t)sh * (T_STEPS * D_IN) + (cbase + stt) * D_IN + scq * 4);
            *reinterpret_cast<float4*>(xst + (sh * TT + stt) * 36 + scq * 4) = v;
        }
        WFENCE();

#pragma unroll 1
        for (int tile = 0; tile < NTILE_C; ++tile) {
            float4 pf = make_float4(0.f, 0.f, 0.f, 0.f);
            const bool more = stg && (tile + 1 < NTILE_C);
            if (more) {
                pf = *reinterpret_cast<const float4*>(
                    tbase + (size_t)sh * (T_STEPS * D_IN)
                          + (cbase + (tile + 1) * TT + stt) * D_IN + scq * 4);
            }
#pragma unroll
            for (int tt = 0; tt < TT; ++tt) {
                const float* xrow = xst + (half * TT + tt) * 36;
                f32x2 acc2 = (f32x2){bcol, 0.0f};
#pragma unroll
                for (int cq = 0; cq < 9; ++cq) {
                    const float4 x4 = *reinterpret_cast<const float4*>(xrow + cq * 4);
                    acc2 = pkfma((f32x2){x4.x, x4.y}, wxp2[2 * cq],     acc2);
                    acc2 = pkfma((f32x2){x4.z, x4.w}, wxp2[2 * cq + 1], acc2);
                }
                if (s < 30) xpj[(tile * TT + tt) * 30 + s] = __float2half(acc2.x + acc2.y);
            }
            WFENCE();   // all lanes done reading this tile before overwrite
            if (more) {
                *reinterpret_cast<float4*>(xst + (sh * TT + stt) * 36 + scq * 4) = pf;
            }
            WFENCE();   // staged writes visible before next tile's reads
        }
    };

    // ---- init scan state ----
    f32x2 y2[5];
#pragma unroll
    for (int k = 0; k < 5; ++k) y2[k] = (f32x2){0.0f, 0.0f};
    float yown = 0.0f;
    if (eo) bcP[s - 10] = 0.0f;     // carried unnormalized z; 0 => p=0 at t=0
    WFENCE();

    refill(0);
    WFENCE();

    // ================= Scan: 2 chunks x 30 steps =================
#pragma unroll 1
    for (int c = 0; c < 2; ++c) {
#pragma unroll 1
        for (int tt = 0; tt < CHT; ++tt) {
            const int t = c * CHT + tt;
            const float dt = dts[t];

            // ---- ODE: yi_q = y_q + tanh(b + y.Wode[:,q])*dt (meaningful on uo) ----
            f32x2 g2 = (f32x2){bode, 0.0f};
#pragma unroll
            for (int k = 0; k < 5; ++k) g2 = pkfma(y2[k], waux2[k], g2);
            const float yis = fmaf(tanh_fast(g2.x + g2.y), dt, yown);
            if (uo) bcYI[s] = yis;
            WFENCE();
            f32x2 yi2[5];
            ldvec(bcYI, yi2);
            const float yi_g = bcYI[gcol];   // own-column yi (scalar, parallel read)

            // ---- gates: pre-activation = xproj(f16, bias folded) + yi-part ----
            const float xa = __half2float(xpj[tt * 30 + s]);  // s>=30 reads pad, unused
            f32x2 ay2 = (f32x2){xa, 0.0f};
#pragma unroll
            for (int k = 0; k < 5; ++k) ay2 = pkfma(yi2[k], wgy2[k], ay2);
            const float uval = sigm_fast(ay2.x + ay2.y);   // u on uo, r on ro
            if (ro) bcR[s - 10] = uval * yi_g;             // publish yr_k = r_k * yi_k
            if (uo) bcU[s] = uval;                         // publish u_k (same fence)
            WFENCE();
            f32x2 yr2[5];
            ldvec(bcR, yr2);

            // ---- candidate + blend on n-lanes: yn = n + u*(yi - n) ----
            f32x2 n2 = (f32x2){xa, 0.0f};
#pragma unroll
            for (int k = 0; k < 5; ++k) n2 = pkfma(yr2[k], wgy2[k], n2);
            const float accN = n2.x + n2.y;
            const float u_n  = bcU[gcol];
            const float yn   = fmaf(u_n, yi_g - accN, accN);
            if (no) bcY[s - 20] = yn;
            WFENCE();
            ldvec(bcY, y2);
            yown = bcY[gcol];                              // carry for next ODE (uo)

            // ---- head: phead += y_pair(kq) . W_mlp rows (loop-invariant addrs) ----
            {
                const float* wr = W_mlp + (size_t)t * (L_DIM * OUT_DIM);
                const f32x2 yh = *reinterpret_cast<const f32x2*>(bcY + hoff);
                phead = fmaf(yh.x, wr[boff], phead);
                phead = fmaf(yh.y, wr[boff + OUT_DIM], phead);
                if (kq == 0) {   // pair 4 (y8,y9) on the col's first lane
                    phead = fmaf(y2[4].x, wr[8 * OUT_DIM + hcol], phead);
                    phead = fmaf(y2[4].y, wr[9 * OUT_DIM + hcol], phead);
                }
            }

            // ---- emitter: logit = b + (z_prev . We_p)/sum(z) + y . We_y ----
            f32x2 zz[10];
#pragma unroll
            for (int j = 0; j < 5; ++j) {
                const float4 z = *reinterpret_cast<const float4*>(bcP + j * 4);
                zz[2 * j] = (f32x2){z.x, z.y}; zz[2 * j + 1] = (f32x2){z.z, z.w};
            }
            f32x2 zd2 = (f32x2){0.0f, 0.0f};
            f32x2 zs2 = (f32x2){0.0f, 0.0f};
#pragma unroll
            for (int j = 0; j < 10; ++j) {
                zd2 = pkfma(zz[j], waux2[j], zd2);
                zs2 = zs2 + zz[j];
            }
            const float pinv = (t == 0) ? 0.0f : rcp_fast(zs2.x + zs2.y);
            f32x2 ev2 = (f32x2){fmaf(zd2.x + zd2.y, pinv, bemit), 0.0f};
#pragma unroll
            for (int k = 0; k < 5; ++k) ev2 = pkfma(y2[k], waux2[10 + k], ev2);
            const float zv = exp2_fast(fminf((ev2.x + ev2.y) * LOG2E, 86.0f));
            if (eo) bcP[s - 10] = zv;
            // no trailing fence: next step's fences precede the z read; bcP is
            // outside the refill staging region, so it survives the chunk boundary.
        }
        if (c == 0) {
            refill(1);      // wave-local; scan state lives in regs + bcP only
            WFENCE();
        }
    }

    // ================= Epilogue: reduce head partials, add static =================
    phead += __shfl_xor(phead, 8, 32);
    phead += __shfl_xor(phead, 16, 32);
    if (s < OUT_DIM) {
        const float* stp = static_data + (size_t)traj * S_STAT;
        const float* wms = W_mlp + (size_t)(T_STEPS * L_DIM) * OUT_DIM;
        float o = phead;
#pragma unroll
        for (int i = 0; i < S_STAT; ++i) o += stp[i] * wms[i * OUT_DIM + s];
        out[(size_t)traj * OUT_DIM + s] = o + b_mlp[s];
    }
}

extern "C" void kernel_launch(void* const* d_in, const int* in_sizes, int n_in,
                              void* d_out, int out_size, void* d_ws, size_t ws_size,
                              hipStream_t stream) {
    const float* data        = (const float*)d_in[0];
    const float* time_steps  = (const float*)d_in[1];
    const float* static_data = (const float*)d_in[2];
    const float* W_update    = (const float*)d_in[3];
    const float* b_update    = (const float*)d_in[4];
    const float* W_reset     = (const float*)d_in[5];
    const float* b_reset     = (const float*)d_in[6];
    const float* W_new       = (const float*)d_in[7];
    const float* b_new       = (const float*)d_in[8];
    const float* W_emit      = (const float*)d_in[9];
    const float* b_emit      = (const float*)d_in[10];
    const float* W_ode       = (const float*)d_in[11];
    const float* b_ode       = (const float*)d_in[12];
    const float* W_mlp       = (const float*)d_in[13];
    const float* b_mlp       = (const float*)d_in[14];
    float* out = (float*)d_out;

    // 4 trajectories per 128-thread block (2 waves) -> 4096 blocks
    dim3 grid(B_TRAJ / 4), block(128);
    hipLaunchKernelGGL(dgm2_v15, grid, block, 0, stream,
                       data, time_steps, static_data,
                       W_update, b_update, W_reset, b_reset, W_new, b_new,
                       W_emit, b_emit, W_ode, b_ode, W_mlp, b_mlp, out);
}